// Round 5
// baseline (332.869 us; speedup 1.0000x reference)
//
#include <hip/hip_runtime.h>

// Problem: nearest = memory[argmax_m cosine(x_row, memory_m)], plus copy of x.
//   x: 65536 x 1024 f32, memory: 40 x 1024 f32, out = [nearest (65536x1024) | x (65536x1024)]
//
// d_ws layout (bytes):
//   [0,   320) : double inv64[40]   (1/max(||mem_m||,eps), f64)
//   [320, 480) : float  inv32[40]
//   [512, 8704): unsigned long long flagbits[1024]  (one bit per x-row, 64 rows/word)

#define DIM 1024
#define NMEM 40

constexpr float TAU = 2.5e-4f;   // normalized top-2 gap below which we re-resolve in f64

// ---------------- Kernel 1: memory-row inverse norms (f32 + f64) ----------------
__global__ __launch_bounds__(64) void k_norms(const float* __restrict__ mem,
                                              double* __restrict__ inv64,
                                              float* __restrict__ inv32) {
  const int m = blockIdx.x;      // 40 blocks, 1 wave each
  const int lane = threadIdx.x;
  const float* __restrict__ row = mem + (size_t)m * DIM;
  double s = 0.0;
#pragma unroll
  for (int i = 0; i < DIM / 64; ++i) {
    double v = (double)row[lane + 64 * i];
    s = fma(v, v, s);
  }
#pragma unroll
  for (int off = 32; off > 0; off >>= 1) s += __shfl_xor(s, off, 64);
  if (lane == 0) {
    double n = sqrt(s);
    n = (n > 1e-8) ? n : 1e-8;
    inv64[m] = 1.0 / n;
    inv32[m] = (float)(1.0 / n);
  }
}

// ---------------- Kernel 2: fused sims + argmax + gather + x-copy ----------------
// Block = 8 waves, 128 x-rows; lane owns rows (lane) and (lane+64). Wave w owns
// memory rows [5w, 5w+5). m-operand loads are FORCED onto the vector path
// (opaque VGPR zero in the address) so they hit L1 as pipelined VMEM instead of
// serialized scalar-cache misses (the R4 bottleneck). Two barriers per 32-float
// K-chunk (empirically best structure); x-copy stores issued in the staging
// phase. Grid 512 blocks = 2/CU, 16 waves/CU.
__global__ __launch_bounds__(512) void k_main(const float* __restrict__ x,
                                              const float* __restrict__ mem,
                                              const float* __restrict__ inv32,
                                              float* __restrict__ out_near,
                                              float* __restrict__ out_x,
                                              unsigned long long* __restrict__ flagbits) {
  __shared__ float4 xt[128 * 9];    // 128 rows x 8 float4 slots, +1 pad (measured: 0 conflicts)
  __shared__ float mv1[8][128];
  __shared__ float mv2[8][128];
  __shared__ int   mi1[8][128];
  __shared__ int   amax[128];

  const int tid  = threadIdx.x;
  const int lane = tid & 63;
  const int w    = __builtin_amdgcn_readfirstlane(tid >> 6); // uniform wave id 0..7
  const int mbase = w * 5;
  const int rowbase = blockIdx.x * 128;

  const float4* __restrict__ x4  = (const float4*)x + (size_t)rowbase * (DIM / 4);
  float4* __restrict__ ox4       = (float4*)out_x  + (size_t)rowbase * (DIM / 4);
  const float4* __restrict__ m4  = (const float4*)mem;

  // opaque zero in a VGPR: defeats uniformity analysis -> m loads stay VMEM
  int vz;
  asm volatile("v_mov_b32 %0, 0" : "=v"(vz));
  const float4* __restrict__ m4v = m4 + vz;

  // staging: 512 threads cover the 128x8 float4 chunk twice (f = tid, tid+512)
  const int rA = tid >> 3,          sA = tid & 7;
  const int rB = (tid + 512) >> 3;  // sB == sA
  const size_t gA = (size_t)rA * (DIM / 4) + sA;
  const size_t gB = (size_t)rB * (DIM / 4) + sA;
  const int lA = rA * 9 + sA, lB = rB * 9 + sA;

  float acc[5], accB[5];
#pragma unroll
  for (int q = 0; q < 5; ++q) { acc[q] = 0.f; accB[q] = 0.f; }
  float nxa = 0.f, nxb = 0.f;   // ||x_row||^2 for rows lane, lane+64 (all waves identical)

  for (int kc = 0; kc < DIM / 32; ++kc) {
    __syncthreads();  // previous chunk's LDS reads done before overwrite
    {
      float4 va = x4[gA + (size_t)kc * 8];
      float4 vb = x4[gB + (size_t)kc * 8];
      ox4[gA + (size_t)kc * 8] = va;   // x-copy from the same registers; x read once
      ox4[gB + (size_t)kc * 8] = vb;
      xt[lA] = va;
      xt[lB] = vb;
    }
    __syncthreads();
#pragma unroll
    for (int k4 = 0; k4 < 8; ++k4) {
      float4 xa = xt[lane * 9 + k4];
      float4 xb = xt[(lane + 64) * 9 + k4];
      nxa = fmaf(xa.x, xa.x, fmaf(xa.y, xa.y, fmaf(xa.z, xa.z, fmaf(xa.w, xa.w, nxa))));
      nxb = fmaf(xb.x, xb.x, fmaf(xb.y, xb.y, fmaf(xb.z, xb.z, fmaf(xb.w, xb.w, nxb))));
#pragma unroll
      for (int q = 0; q < 5; ++q) {
        float4 mv = m4v[(size_t)(mbase + q) * (DIM / 4) + kc * 8 + k4];  // VMEM, L1-hot
        acc[q]  = fmaf(xa.x, mv.x, fmaf(xa.y, mv.y, fmaf(xa.z, mv.z, fmaf(xa.w, mv.w, acc[q]))));
        accB[q] = fmaf(xb.x, mv.x, fmaf(xb.y, mv.y, fmaf(xb.z, mv.z, fmaf(xb.w, mv.w, accB[q]))));
      }
    }
  }

  // per-lane top-2 over this wave's 5 m's, for both owned rows
  float v1a = -3.4e38f, v2a = -3.4e38f, v1b = -3.4e38f, v2b = -3.4e38f;
  int i1a = 0, i1b = 0;
#pragma unroll
  for (int q = 0; q < 5; ++q) {
    float va = acc[q]  * inv32[mbase + q];   // ||x|| factor common to all m -> argmax-invariant
    float vb = accB[q] * inv32[mbase + q];
    if (va > v1a) { v2a = v1a; v1a = va; i1a = mbase + q; } else if (va > v2a) v2a = va;
    if (vb > v1b) { v2b = v1b; v1b = vb; i1b = mbase + q; } else if (vb > v2b) v2b = vb;
  }
  mv1[w][lane] = v1a; mv2[w][lane] = v2a; mi1[w][lane] = i1a;
  mv1[w][lane + 64] = v1b; mv2[w][lane + 64] = v2b; mi1[w][lane + 64] = i1b;
  __syncthreads();

  if (w == 0) {
#pragma unroll
    for (int h = 0; h < 2; ++h) {
      const int r = lane + 64 * h;
      float b1 = mv1[0][r], b2 = mv2[0][r];
      int bi = mi1[0][r];
#pragma unroll
      for (int g = 1; g < 8; ++g) {
        float a1 = mv1[g][r], a2 = mv2[g][r];
        int ai = mi1[g][r];
        if (a1 > b1) { b2 = fmaxf(b1, a2); b1 = a1; bi = ai; }  // ascending g => ties keep lower m
        else         { b2 = fmaxf(b2, a1); }
      }
      float nx = h ? nxb : nxa;                           // wave 0's own accumulation
      float gap = (b1 - b2) * rsqrtf(fmaxf(nx, 1e-30f));  // normalized top-2 gap
      bool flag = !(gap >= TAU);                          // NaN-safe: NaN -> flagged
      unsigned long long mask = __ballot(flag);
      if (lane == 0) flagbits[blockIdx.x * 2 + h] = mask; // all 1024 words written every call
      amax[r] = bi;
    }
  }
  __syncthreads();

  // gather-copy memory[amax] -> out_near, coalesced (each wave does 16 rows)
  float4* __restrict__ on4 = (float4*)out_near + (size_t)rowbase * (DIM / 4);
#pragma unroll 1
  for (int rr = 0; rr < 16; ++rr) {
    int r = (tid >> 6) * 16 + rr;
    int am = amax[r];
    const float4* __restrict__ src = m4 + (size_t)am * (DIM / 4);
    float4* __restrict__ dst = on4 + (size_t)r * (DIM / 4);
#pragma unroll
    for (int j = 0; j < 4; ++j) dst[lane + 64 * j] = src[lane + 64 * j];
  }
}

// ---------------- Kernel 3: f64 re-resolution of razor-thin rows ----------------
__global__ __launch_bounds__(256) void k_refine(const float* __restrict__ x,
                                                const float* __restrict__ mem,
                                                const double* __restrict__ inv64,
                                                const unsigned long long* __restrict__ flagbits,
                                                float* __restrict__ out_near) {
  unsigned long long mask = flagbits[blockIdx.x];
  if (mask == 0ull) return;                 // uniform; nearly all blocks exit here
  const int tid = threadIdx.x;
  const int lane = tid & 63;
  const int wid = tid >> 6;
  __shared__ double bval[4];
  __shared__ int bidx[4];
  while (mask) {
    int r = __ffsll(mask) - 1;
    mask &= (mask - 1ull);
    int row = blockIdx.x * 64 + r;
    const float* __restrict__ xr = x + (size_t)row * DIM;
    double xd[16];
#pragma unroll
    for (int i = 0; i < 16; ++i) xd[i] = (double)xr[lane + 64 * i];
    double best = -1e300;
    int bi = 0;
    for (int q = 0; q < 10; ++q) {
      int m = wid * 10 + q;
      const float* __restrict__ mr = mem + (size_t)m * DIM;
      double s = 0.0;
#pragma unroll
      for (int i = 0; i < 16; ++i) s = fma(xd[i], (double)mr[lane + 64 * i], s);
#pragma unroll
      for (int off = 32; off > 0; off >>= 1) s += __shfl_xor(s, off, 64);
      double v = s * inv64[m];              // identical (bitwise) across lanes
      if (v > best) { best = v; bi = m; }   // strict > keeps lowest m on ties
    }
    if (lane == 0) { bval[wid] = best; bidx[wid] = bi; }
    __syncthreads();
    double g = bval[0];
    int gi = bidx[0];
#pragma unroll
    for (int gg = 1; gg < 4; ++gg) {
      if (bval[gg] > g) { g = bval[gg]; gi = bidx[gg]; }
    }
    const float4* __restrict__ src = (const float4*)mem + (size_t)gi * (DIM / 4);
    float4* __restrict__ dst = (float4*)out_near + (size_t)row * (DIM / 4);
    dst[tid] = src[tid];                    // 256 x 16B = full row, coalesced
    __syncthreads();                        // LDS reuse guard for next flagged row
  }
}

extern "C" void kernel_launch(void* const* d_in, const int* in_sizes, int n_in,
                              void* d_out, int out_size, void* d_ws, size_t ws_size,
                              hipStream_t stream) {
  const float* x   = (const float*)d_in[0];
  const float* mem = (const float*)d_in[1];
  // d_in[2] = top_k (unused: reference only consumes idx[:,0], i.e. the argmax)

  const int n_rows = in_sizes[0] / DIM;          // 65536
  float* out_near = (float*)d_out;
  float* out_x    = (float*)d_out + (size_t)n_rows * DIM;

  double* inv64 = (double*)d_ws;
  float*  inv32 = (float*)((char*)d_ws + 320);
  unsigned long long* flagbits = (unsigned long long*)((char*)d_ws + 512);

  hipLaunchKernelGGL(k_norms,  dim3(NMEM), dim3(64),  0, stream, mem, inv64, inv32);
  hipLaunchKernelGGL(k_main,   dim3(n_rows / 128), dim3(512), 0, stream,
                     x, mem, inv32, out_near, out_x, flagbits);
  hipLaunchKernelGGL(k_refine, dim3(n_rows / 64),  dim3(256), 0, stream,
                     x, mem, inv64, flagbits, out_near);
}